// Round 2
// baseline (10852.969 us; speedup 1.0000x reference)
//
#include <hip/hip_runtime.h>
#include <cstdint>

#define NNODES 100000
#define NEDGES 600000
#define NETYPES 4
#define DIM 128
#define NSTEPS 8
#define NGRAPHS 128

__device__ inline unsigned short f2bf(float x) {
  unsigned int u = __float_as_uint(x);
  unsigned int r = (u + 0x7FFFu + ((u >> 16) & 1u)) >> 16;
  return (unsigned short)r;
}
__device__ inline float bf2f(unsigned short b) {
  return __uint_as_float(((unsigned int)b) << 16);
}

// ---------------- transpose W [384][128] -> WT [128][384] ----------------
__global__ __launch_bounds__(256) void transpose_w_kernel(const float* __restrict__ W,
                                                          float* __restrict__ WT) {
  int idx = blockIdx.x * 256 + threadIdx.x;
  if (idx < 384 * DIM) {
    int r = idx / DIM, c = idx % DIM;
    WT[c * 384 + r] = W[idx];
  }
}

// ---------------- diagnostic fill ----------------
__global__ __launch_bounds__(128) void fill_kernel(float* __restrict__ out, int n, float v) {
  int i = blockIdx.x * 128 + threadIdx.x;
  if (i < n) out[i] = v;
}

// ---------------- ht_e = h @ W_edge[ty] (single etype) ----------------
// grid: ceil(N/64), block 256. BM=64, BN=128, BK=32.
template <bool BF16OUT>
__global__ __launch_bounds__(256) void gemm_ht_kernel(const float* __restrict__ h,
                                                      const float* __restrict__ B,
                                                      void* __restrict__ ht_e) {
  const int n0 = blockIdx.x * 64;

  __shared__ float As[32][68];   // [k][n]
  __shared__ float Bs[32][128];  // [k][j]

  const int t = threadIdx.x;
  const int jb = (t & 31) * 4;   // 4 consecutive j
  const int nb = (t >> 5) * 8;   // 8 consecutive n

  float acc[8][4];
#pragma unroll
  for (int i = 0; i < 8; ++i)
#pragma unroll
    for (int q = 0; q < 4; ++q) acc[i][q] = 0.f;

  for (int k0 = 0; k0 < DIM; k0 += 32) {
#pragma unroll
    for (int l = 0; l < 2; ++l) {  // A tile 64x32 -> LDS transposed
      int idx = t + l * 256;
      int r = idx >> 3;
      int c4 = (idx & 7) * 4;
      int n = n0 + r;
      float4 v = make_float4(0.f, 0.f, 0.f, 0.f);
      if (n < NNODES) v = *(const float4*)(h + (size_t)n * DIM + k0 + c4);
      As[c4 + 0][r] = v.x;
      As[c4 + 1][r] = v.y;
      As[c4 + 2][r] = v.z;
      As[c4 + 3][r] = v.w;
    }
#pragma unroll
    for (int l = 0; l < 4; ++l) {  // B tile 32x128
      int idx = t + l * 256;
      int r = idx >> 5;
      int c4 = (idx & 31) * 4;
      *(float4*)&Bs[r][c4] = *(const float4*)(B + (size_t)(k0 + r) * DIM + c4);
    }
    __syncthreads();
#pragma unroll
    for (int k = 0; k < 32; ++k) {
      float4 b = *(const float4*)&Bs[k][jb];
      float4 A0 = *(const float4*)&As[k][nb];
      float4 A1 = *(const float4*)&As[k][nb + 4];
      float av[8] = {A0.x, A0.y, A0.z, A0.w, A1.x, A1.y, A1.z, A1.w};
#pragma unroll
      for (int i = 0; i < 8; ++i) {
        acc[i][0] = fmaf(av[i], b.x, acc[i][0]);
        acc[i][1] = fmaf(av[i], b.y, acc[i][1]);
        acc[i][2] = fmaf(av[i], b.z, acc[i][2]);
        acc[i][3] = fmaf(av[i], b.w, acc[i][3]);
      }
    }
    __syncthreads();
  }
#pragma unroll
  for (int i = 0; i < 8; ++i) {
    int n = n0 + nb + i;
    if (n < NNODES) {
      if (BF16OUT) {
        ushort4 u;
        u.x = f2bf(acc[i][0]);
        u.y = f2bf(acc[i][1]);
        u.z = f2bf(acc[i][2]);
        u.w = f2bf(acc[i][3]);
        *(ushort4*)((unsigned short*)ht_e + (size_t)n * DIM + jb) = u;
      } else {
        *(float4*)((float*)ht_e + (size_t)n * DIM + jb) =
            make_float4(acc[i][0], acc[i][1], acc[i][2], acc[i][3]);
      }
    }
  }
}

// ---------------- per-edge gather + atomic scatter-add (type-filtered) -----
template <bool BF16MSG>
__global__ __launch_bounds__(256) void scatter_edges_kernel(const void* __restrict__ ht_e,
                                                            const int* __restrict__ esrc,
                                                            const int* __restrict__ edst,
                                                            const int* __restrict__ etyp,
                                                            float* __restrict__ a, int ty) {
  int gw = (blockIdx.x * 256 + threadIdx.x) >> 6;  // wave per edge
  int lane = threadIdx.x & 63;
  int nw = (gridDim.x * 256) >> 6;
  for (int e = gw; e < NEDGES; e += nw) {
    if (etyp[e] != ty) continue;
    int s = esrc[e];
    int d = edst[e];
    float vx, vy;
    if (BF16MSG) {
      ushort2 u = *((const ushort2*)ht_e + ((size_t)s * DIM >> 1) + lane);
      vx = bf2f(u.x);
      vy = bf2f(u.y);
    } else {
      float2 v = *((const float2*)ht_e + ((size_t)s * DIM >> 1) + lane);
      vx = v.x;
      vy = v.y;
    }
    float* ap = a + (size_t)d * DIM + lane * 2;
    atomicAdd(ap, vx);
    atomicAdd(ap + 1, vy);
  }
}

// ---------------- fused GRU: h = GRU(a, h) ----------------
// grid: N/16 blocks of 256. BM=16 nodes, all 384 outputs x2 matrices, BK=16.
__global__ __launch_bounds__(256) void gru_fused_kernel(const float* __restrict__ a,
                                                        float* __restrict__ h,
                                                        const float* __restrict__ WihT,
                                                        const float* __restrict__ WhhT,
                                                        const float* __restrict__ b_ih,
                                                        const float* __restrict__ b_hh) {
  const int n0 = blockIdx.x * 16;
  __shared__ float a_s[16][17];    // [k][n]
  __shared__ float h_s[16][17];
  __shared__ float Wih_s[16][384]; // [k][j']
  __shared__ float Whh_s[16][384];

  const int t = threadIdx.x;
  const int jb = (t & 31) * 4;  // j in [0,128)
  const int na = (t >> 5) * 2;  // 2 nodes per thread

  float gi[3][2][4], gh[3][2][4];
#pragma unroll
  for (int s = 0; s < 3; ++s)
#pragma unroll
    for (int i = 0; i < 2; ++i)
#pragma unroll
      for (int q = 0; q < 4; ++q) { gi[s][i][q] = 0.f; gh[s][i][q] = 0.f; }

  for (int k0 = 0; k0 < DIM; k0 += 16) {
    if (t < 64) {
      int n = t >> 2, c4 = (t & 3) * 4;
      float4 v = *(const float4*)(a + (size_t)(n0 + n) * DIM + k0 + c4);
      a_s[c4 + 0][n] = v.x; a_s[c4 + 1][n] = v.y; a_s[c4 + 2][n] = v.z; a_s[c4 + 3][n] = v.w;
    } else if (t < 128) {
      int tt = t - 64;
      int n = tt >> 2, c4 = (tt & 3) * 4;
      float4 v = *(const float4*)(h + (size_t)(n0 + n) * DIM + k0 + c4);
      h_s[c4 + 0][n] = v.x; h_s[c4 + 1][n] = v.y; h_s[c4 + 2][n] = v.z; h_s[c4 + 3][n] = v.w;
    }
#pragma unroll
    for (int l = 0; l < 6; ++l) {
      int idx = t + l * 256;
      int r = idx / 96;
      int c4 = (idx % 96) * 4;
      *(float4*)&Wih_s[r][c4] = *(const float4*)(WihT + (size_t)(k0 + r) * 384 + c4);
      *(float4*)&Whh_s[r][c4] = *(const float4*)(WhhT + (size_t)(k0 + r) * 384 + c4);
    }
    __syncthreads();
#pragma unroll
    for (int k = 0; k < 16; ++k) {
      float a0 = a_s[k][na], a1 = a_s[k][na + 1];
      float h0 = h_s[k][na], h1 = h_s[k][na + 1];
#pragma unroll
      for (int s = 0; s < 3; ++s) {
        float4 wi = *(const float4*)&Wih_s[k][s * 128 + jb];
        float4 wh = *(const float4*)&Whh_s[k][s * 128 + jb];
        gi[s][0][0] = fmaf(a0, wi.x, gi[s][0][0]);
        gi[s][0][1] = fmaf(a0, wi.y, gi[s][0][1]);
        gi[s][0][2] = fmaf(a0, wi.z, gi[s][0][2]);
        gi[s][0][3] = fmaf(a0, wi.w, gi[s][0][3]);
        gi[s][1][0] = fmaf(a1, wi.x, gi[s][1][0]);
        gi[s][1][1] = fmaf(a1, wi.y, gi[s][1][1]);
        gi[s][1][2] = fmaf(a1, wi.z, gi[s][1][2]);
        gi[s][1][3] = fmaf(a1, wi.w, gi[s][1][3]);
        gh[s][0][0] = fmaf(h0, wh.x, gh[s][0][0]);
        gh[s][0][1] = fmaf(h0, wh.y, gh[s][0][1]);
        gh[s][0][2] = fmaf(h0, wh.z, gh[s][0][2]);
        gh[s][0][3] = fmaf(h0, wh.w, gh[s][0][3]);
        gh[s][1][0] = fmaf(h1, wh.x, gh[s][1][0]);
        gh[s][1][1] = fmaf(h1, wh.y, gh[s][1][1]);
        gh[s][1][2] = fmaf(h1, wh.z, gh[s][1][2]);
        gh[s][1][3] = fmaf(h1, wh.w, gh[s][1][3]);
      }
    }
    __syncthreads();
  }
#pragma unroll
  for (int i = 0; i < 2; ++i) {
    int n = n0 + na + i;
    float4 hold = *(const float4*)(h + (size_t)n * DIM + jb);
    float ho[4] = {hold.x, hold.y, hold.z, hold.w};
    float out[4];
#pragma unroll
    for (int q = 0; q < 4; ++q) {
      int j = jb + q;
      float ir = gi[0][i][q] + b_ih[j];
      float iz = gi[1][i][q] + b_ih[j + 128];
      float inn = gi[2][i][q] + b_ih[j + 256];
      float hr = gh[0][i][q] + b_hh[j];
      float hz = gh[1][i][q] + b_hh[j + 128];
      float hn = gh[2][i][q] + b_hh[j + 256];
      float r = 1.f / (1.f + __expf(-(ir + hr)));
      float z = 1.f / (1.f + __expf(-(iz + hz)));
      float x = inn + r * hn;
      float ex = __expf(2.f * x);
      float nn = 1.f - 2.f / (ex + 1.f);  // tanh
      out[q] = (1.f - z) * nn + z * ho[q];
    }
    *(float4*)(h + (size_t)n * DIM + jb) = make_float4(out[0], out[1], out[2], out[3]);
  }
}

// ---------------- pooled[g] = sum_{gid[n]==g} h[n] ----------------
__global__ __launch_bounds__(128) void pool_kernel(const float* __restrict__ h,
                                                   const int* __restrict__ gid,
                                                   float* __restrict__ pooled) {
  int j = threadIdx.x;
  int n0 = blockIdx.x * 32;
  int end = n0 + 32;
  if (end > NNODES) end = NNODES;
  int cur = gid[n0];
  float acc = 0.f;
  for (int n = n0; n < end; ++n) {
    int g = gid[n];
    if (g != cur) {
      atomicAdd(&pooled[cur * DIM + j], acc);
      acc = 0.f;
      cur = g;
    }
    acc += h[(size_t)n * DIM + j];
  }
  atomicAdd(&pooled[cur * DIM + j], acc);
}

// ---------------- logits + sigmoid ----------------
__global__ __launch_bounds__(128) void cls_kernel(const float* __restrict__ pooled,
                                                  const float* __restrict__ Wc,
                                                  const float* __restrict__ bc,
                                                  float* __restrict__ out) {
  int g = threadIdx.x;
  float acc = bc[0];
  for (int k = 0; k < DIM; ++k) acc = fmaf(pooled[g * DIM + k], Wc[k], acc);
  out[g] = 1.f / (1.f + __expf(-acc));
}

extern "C" void kernel_launch(void* const* d_in, const int* in_sizes, int n_in,
                              void* d_out, int out_size, void* d_ws, size_t ws_size,
                              hipStream_t stream) {
  const float* features = (const float*)d_in[0];
  const int* esrc = (const int*)d_in[1];
  const int* edst = (const int*)d_in[2];
  const int* etyp = (const int*)d_in[3];
  const int* gids = (const int*)d_in[4];
  const float* W_edge = (const float*)d_in[5];
  const float* W_ih = (const float*)d_in[6];
  const float* W_hh = (const float*)d_in[7];
  const float* b_ih = (const float*)d_in[8];
  const float* b_hh = (const float*)d_in[9];
  const float* W_cls = (const float*)d_in[10];
  const float* b_cls = (const float*)d_in[11];
  float* out = (float*)d_out;

  const size_t nd = (size_t)NNODES * DIM;
  const size_t tail = (2 * 128 * 384 + NGRAPHS * DIM) * sizeof(float);
  const size_t need_f32 = nd * 4 * 3 + tail;             // ht_e fp32 + a + h
  const size_t need_bf16 = nd * 2 + nd * 4 * 2 + tail;   // ht_e bf16 + a + h

  if (ws_size < need_bf16) {
    // diagnostic: distinctive non-crashing output
    fill_kernel<<<(out_size + 127) / 128, 128, 0, stream>>>(out, out_size, 0.5f);
    return;
  }
  const bool f32ht = (ws_size >= need_f32);

  char* p = (char*)d_ws;
  void* ht_e = (void*)p; p += f32ht ? nd * 4 : nd * 2;
  float* a = (float*)p;  p += nd * 4;
  float* h = (float*)p;  p += nd * 4;
  float* WihT = (float*)p; p += 128 * 384 * 4;
  float* WhhT = (float*)p; p += 128 * 384 * 4;
  float* pooled = (float*)p;

  hipMemcpyAsync(h, features, nd * sizeof(float), hipMemcpyDeviceToDevice, stream);
  transpose_w_kernel<<<(384 * DIM + 255) / 256, 256, 0, stream>>>(W_ih, WihT);
  transpose_w_kernel<<<(384 * DIM + 255) / 256, 256, 0, stream>>>(W_hh, WhhT);

  const int gemm_grid = (NNODES + 63) / 64;
  for (int s = 0; s < NSTEPS; ++s) {
    hipMemsetAsync(a, 0, nd * sizeof(float), stream);
    for (int ty = 0; ty < NETYPES; ++ty) {
      const float* B = W_edge + (size_t)ty * DIM * DIM;
      if (f32ht) {
        gemm_ht_kernel<false><<<gemm_grid, 256, 0, stream>>>(h, B, ht_e);
        scatter_edges_kernel<false><<<2048, 256, 0, stream>>>(ht_e, esrc, edst, etyp, a, ty);
      } else {
        gemm_ht_kernel<true><<<gemm_grid, 256, 0, stream>>>(h, B, ht_e);
        scatter_edges_kernel<true><<<2048, 256, 0, stream>>>(ht_e, esrc, edst, etyp, a, ty);
      }
    }
    gru_fused_kernel<<<NNODES / 16, 256, 0, stream>>>(a, h, WihT, WhhT, b_ih, b_hh);
  }

  hipMemsetAsync(pooled, 0, (size_t)NGRAPHS * DIM * sizeof(float), stream);
  pool_kernel<<<(NNODES + 31) / 32, 128, 0, stream>>>(h, gids, pooled);
  cls_kernel<<<1, 128, 0, stream>>>(pooled, W_cls, b_cls, out);
}

// Round 3
// 2412.665 us; speedup vs baseline: 4.4983x; 4.4983x over previous
//
#include <hip/hip_runtime.h>
#include <cstdint>

#define NNODES 100000
#define NEDGES 600000
#define NETYPES 4
#define DIM 128
#define NSTEPS 8
#define NGRAPHS 128
#define NBINS (NETYPES * NNODES)
#define SCAN_BLK 391  // ceil(NBINS/1024)

typedef short s16x8 __attribute__((ext_vector_type(8)));
typedef float f32x4 __attribute__((ext_vector_type(4)));

#define MFMA(a, b, c) __builtin_amdgcn_mfma_f32_16x16x32_bf16(a, b, c, 0, 0, 0)

static __device__ inline unsigned short f2bf(float x) {
  unsigned int u = __float_as_uint(x);
  unsigned int r = (u + 0x7FFFu + ((u >> 16) & 1u)) >> 16;
  return (unsigned short)r;
}
static __device__ inline float bf2f(unsigned short b) {
  return __uint_as_float(((unsigned int)b) << 16);
}

// ---------------- diagnostic fill ----------------
__global__ __launch_bounds__(128) void fill_kernel(float* __restrict__ out, int n, float v) {
  int i = blockIdx.x * 128 + threadIdx.x;
  if (i < n) out[i] = v;
}

// ---------------- fp32 -> bf16 converts ----------------
__global__ __launch_bounds__(256) void cvt_h_kernel(const float* __restrict__ f,
                                                    unsigned short* __restrict__ h, int n4) {
  int i = blockIdx.x * 256 + threadIdx.x;
  if (i < n4) {
    float4 v = ((const float4*)f)[i];
    ushort4 u = {f2bf(v.x), f2bf(v.y), f2bf(v.z), f2bf(v.w)};
    ((ushort4*)h)[i] = u;
  }
}

// W_edge [e][d][h] fp32 -> WeT [e][h][d] bf16 (j-major, k-contiguous)
__global__ __launch_bounds__(256) void cvt_we_kernel(const float* __restrict__ W,
                                                     unsigned short* __restrict__ WT) {
  int i = blockIdx.x * 256 + threadIdx.x;
  if (i < NETYPES * DIM * DIM) {
    int e = i >> 14;
    int r = i & 16383;
    int d = r >> 7;    // k
    int j = r & 127;   // output col
    WT[(e << 14) + (j << 7) + d] = f2bf(W[i]);
  }
}

// straight elementwise convert (W_ih/W_hh are already [j][k])
__global__ __launch_bounds__(256) void cvt_w_kernel(const float* __restrict__ W,
                                                    unsigned short* __restrict__ Wb, int n) {
  int i = blockIdx.x * 256 + threadIdx.x;
  if (i < n) Wb[i] = f2bf(W[i]);
}

// ---------------- CSR build: histogram / scan / fill ----------------
__global__ __launch_bounds__(256) void hist_kernel(const int* __restrict__ edst,
                                                   const int* __restrict__ etyp,
                                                   int* __restrict__ bins) {
  int e = blockIdx.x * 256 + threadIdx.x;
  if (e < NEDGES) atomicAdd(&bins[etyp[e] * NNODES + edst[e]], 1);
}

__global__ __launch_bounds__(256) void scan1_kernel(const int* __restrict__ bins,
                                                    int* __restrict__ rp,
                                                    int* __restrict__ bsum) {
  __shared__ int sh[256];
  int b = blockIdx.x, t = threadIdx.x;
  int base = b * 1024 + t * 4;
  int v0 = 0, v1 = 0, v2 = 0, v3 = 0;
  if (base + 3 < NBINS) {
    int4 q = *(const int4*)(bins + base);
    v0 = q.x; v1 = q.y; v2 = q.z; v3 = q.w;
  } else {
    if (base < NBINS) v0 = bins[base];
    if (base + 1 < NBINS) v1 = bins[base + 1];
    if (base + 2 < NBINS) v2 = bins[base + 2];
  }
  int s = v0 + v1 + v2 + v3;
  sh[t] = s;
  __syncthreads();
  for (int off = 1; off < 256; off <<= 1) {
    int x = (t >= off) ? sh[t - off] : 0;
    __syncthreads();
    if (t >= off) sh[t] += x;
    __syncthreads();
  }
  int run = sh[t] - s;  // exclusive within block
  if (t == 255) bsum[b] = sh[255];
  if (base < NBINS) rp[base] = run;
  run += v0;
  if (base + 1 < NBINS) rp[base + 1] = run;
  run += v1;
  if (base + 2 < NBINS) rp[base + 2] = run;
  run += v2;
  if (base + 3 < NBINS) rp[base + 3] = run;
}

__global__ __launch_bounds__(512) void scan2_kernel(const int* __restrict__ bsum,
                                                    int* __restrict__ boffs,
                                                    int* __restrict__ rp) {
  __shared__ int sh[512];
  int t = threadIdx.x;
  int v = (t < SCAN_BLK) ? bsum[t] : 0;
  sh[t] = v;
  __syncthreads();
  for (int off = 1; off < 512; off <<= 1) {
    int x = (t >= off) ? sh[t - off] : 0;
    __syncthreads();
    if (t >= off) sh[t] += x;
    __syncthreads();
  }
  if (t < SCAN_BLK) boffs[t] = sh[t] - v;
  if (t == SCAN_BLK - 1) rp[NBINS] = sh[t];  // total == NEDGES
}

__global__ __launch_bounds__(256) void scan3_kernel(int* __restrict__ rp,
                                                    const int* __restrict__ boffs) {
  int b = blockIdx.x, t = threadIdx.x;
  int base = b * 1024 + t * 4;
  int off = boffs[b];
#pragma unroll
  for (int i = 0; i < 4; ++i)
    if (base + i < NBINS) rp[base + i] += off;
}

__global__ __launch_bounds__(256) void fill_edges_kernel(const int* __restrict__ esrc,
                                                         const int* __restrict__ edst,
                                                         const int* __restrict__ etyp,
                                                         int* __restrict__ cursor,
                                                         int* __restrict__ esrc_s) {
  int e = blockIdx.x * 256 + threadIdx.x;
  if (e < NEDGES) {
    int slot = atomicAdd(&cursor[etyp[e] * NNODES + edst[e]], 1);
    esrc_s[slot] = esrc[e];
  }
}

// ---------------- ht4[ty] = h @ W_edge[ty], bf16 MFMA ----------------
// grid (782, 4), block 256. Wave = 32 rows x 128 cols. No LDS.
__global__ __launch_bounds__(256) void gemm_ht4_kernel(const unsigned short* __restrict__ hbf,
                                                       const unsigned short* __restrict__ WeT,
                                                       unsigned short* __restrict__ ht4) {
  const int ty = blockIdx.y;
  const int n0 = blockIdx.x * 128;
  const int wid = threadIdx.x >> 6, lane = threadIdx.x & 63;
  const int l15 = lane & 15, kg = lane >> 4;
  const unsigned short* WT = WeT + (ty << 14);
  unsigned short* C = ht4 + (size_t)ty * NNODES * DIM;
  const int rbase = n0 + wid * 32;

  f32x4 acc[2][8];
#pragma unroll
  for (int mb = 0; mb < 2; ++mb)
#pragma unroll
    for (int jf = 0; jf < 8; ++jf) acc[mb][jf] = (f32x4){0.f, 0.f, 0.f, 0.f};

#pragma unroll
  for (int c = 0; c < 4; ++c) {
    s16x8 af[2];
#pragma unroll
    for (int mb = 0; mb < 2; ++mb) {
      int r = rbase + mb * 16 + l15;
      if (r < NNODES)
        af[mb] = *(const s16x8*)(hbf + (size_t)r * DIM + c * 32 + kg * 8);
      else
        af[mb] = (s16x8){0, 0, 0, 0, 0, 0, 0, 0};
    }
#pragma unroll
    for (int jf = 0; jf < 8; ++jf) {
      s16x8 wf = *(const s16x8*)(WT + ((jf * 16 + l15) << 7) + c * 32 + kg * 8);
      acc[0][jf] = MFMA(wf, af[0], acc[0][jf]);
      acc[1][jf] = MFMA(wf, af[1], acc[1][jf]);
    }
  }
  // D[j_local = kg*4+reg][n_local = l15]
#pragma unroll
  for (int mb = 0; mb < 2; ++mb) {
    int n = rbase + mb * 16 + l15;
    if (n < NNODES) {
#pragma unroll
      for (int jf = 0; jf < 8; ++jf) {
        ushort4 u = {f2bf(acc[mb][jf][0]), f2bf(acc[mb][jf][1]),
                     f2bf(acc[mb][jf][2]), f2bf(acc[mb][jf][3])};
        *(ushort4*)(C + (size_t)n * DIM + jf * 16 + kg * 4) = u;
      }
    }
  }
}

// ---------------- a[d] = sum over CSR in-edges of ht4[ty][src], bf16 out ----
// one wave per node, no atomics
__global__ __launch_bounds__(256) void aggregate_kernel(const unsigned short* __restrict__ ht4,
                                                        const int* __restrict__ rp,
                                                        const int* __restrict__ esrc_s,
                                                        unsigned short* __restrict__ abf) {
  int w = (blockIdx.x * 256 + threadIdx.x) >> 6;
  int lane = threadIdx.x & 63;
  if (w >= NNODES) return;
  float ax = 0.f, ay = 0.f;
#pragma unroll
  for (int ty = 0; ty < NETYPES; ++ty) {
    int beg = rp[ty * NNODES + w];
    int end = rp[ty * NNODES + w + 1];
    const unsigned short* base = ht4 + (size_t)ty * NNODES * DIM;
    for (int e = beg; e < end; ++e) {
      int s = esrc_s[e];
      ushort2 u = *(const ushort2*)(base + (size_t)s * DIM + lane * 2);
      ax += bf2f(u.x);
      ay += bf2f(u.y);
    }
  }
  unsigned int packed = ((unsigned int)f2bf(ay) << 16) | (unsigned int)f2bf(ax);
  *(unsigned int*)(abf + (size_t)w * DIM + lane * 2) = packed;
}

// ---------------- fused GRU via MFMA: h = GRU(a, h), in-place bf16 --------
// grid 3125, block 256. Wave = 32 nodes x 32 cols (all 6 gate slices).
__global__ __launch_bounds__(256) void gru_mfma_kernel(const unsigned short* __restrict__ abf,
                                                       unsigned short* __restrict__ hbf,
                                                       const unsigned short* __restrict__ Wih,
                                                       const unsigned short* __restrict__ Whh,
                                                       const float* __restrict__ b_ih,
                                                       const float* __restrict__ b_hh) {
  const int n0 = blockIdx.x * 32;
  const int wid = threadIdx.x >> 6, lane = threadIdx.x & 63;
  const int l15 = lane & 15, kg = lane >> 4;
  const int j0 = wid * 32;

  f32x4 gi[3][2][2], gh[3][2][2];  // [gate][jj][nb]
#pragma unroll
  for (int g = 0; g < 3; ++g)
#pragma unroll
    for (int jj = 0; jj < 2; ++jj)
#pragma unroll
      for (int nb = 0; nb < 2; ++nb) {
        gi[g][jj][nb] = (f32x4){0.f, 0.f, 0.f, 0.f};
        gh[g][jj][nb] = (f32x4){0.f, 0.f, 0.f, 0.f};
      }

#pragma unroll
  for (int c = 0; c < 4; ++c) {
    s16x8 afr[2], hfr[2];
#pragma unroll
    for (int nb = 0; nb < 2; ++nb) {
      int r = n0 + nb * 16 + l15;
      afr[nb] = *(const s16x8*)(abf + (size_t)r * DIM + c * 32 + kg * 8);
      hfr[nb] = *(const s16x8*)(hbf + (size_t)r * DIM + c * 32 + kg * 8);
    }
#pragma unroll
    for (int g = 0; g < 3; ++g)
#pragma unroll
      for (int jj = 0; jj < 2; ++jj) {
        int jrow = g * 128 + j0 + jj * 16 + l15;
        s16x8 wi = *(const s16x8*)(Wih + (jrow << 7) + c * 32 + kg * 8);
        s16x8 wh = *(const s16x8*)(Whh + (jrow << 7) + c * 32 + kg * 8);
        gi[g][jj][0] = MFMA(wi, afr[0], gi[g][jj][0]);
        gi[g][jj][1] = MFMA(wi, afr[1], gi[g][jj][1]);
        gh[g][jj][0] = MFMA(wh, hfr[0], gh[g][jj][0]);
        gh[g][jj][1] = MFMA(wh, hfr[1], gh[g][jj][1]);
      }
  }

  __syncthreads();  // all h reads done before any wave writes h

  // D element: j = j0 + jj*16 + kg*4 + reg ; n = n0 + nb*16 + l15
#pragma unroll
  for (int nb = 0; nb < 2; ++nb) {
    int n = n0 + nb * 16 + l15;
#pragma unroll
    for (int jj = 0; jj < 2; ++jj) {
      int jb = j0 + jj * 16 + kg * 4;
      ushort4 hold4 = *(const ushort4*)(hbf + (size_t)n * DIM + jb);
      ushort4 outu;
#pragma unroll
      for (int reg = 0; reg < 4; ++reg) {
        int j = jb + reg;
        float ir = gi[0][jj][nb][reg] + b_ih[j];
        float iz = gi[1][jj][nb][reg] + b_ih[j + 128];
        float in_ = gi[2][jj][nb][reg] + b_ih[j + 256];
        float hr = gh[0][jj][nb][reg] + b_hh[j];
        float hz = gh[1][jj][nb][reg] + b_hh[j + 128];
        float hn = gh[2][jj][nb][reg] + b_hh[j + 256];
        float r = 1.f / (1.f + __expf(-(ir + hr)));
        float z = 1.f / (1.f + __expf(-(iz + hz)));
        float x = in_ + r * hn;
        float ex = __expf(2.f * x);
        float nn = 1.f - 2.f / (ex + 1.f);  // tanh
        float ho = bf2f(((const unsigned short*)&hold4)[reg]);
        float hv = (1.f - z) * nn + z * ho;
        ((unsigned short*)&outu)[reg] = f2bf(hv);
      }
      *(ushort4*)(hbf + (size_t)n * DIM + jb) = outu;
    }
  }
}

// ---------------- pooled[g] = sum_{gid[n]==g} h[n] ----------------
__global__ __launch_bounds__(128) void pool_kernel(const unsigned short* __restrict__ h,
                                                   const int* __restrict__ gid,
                                                   float* __restrict__ pooled) {
  int j = threadIdx.x;
  int n0 = blockIdx.x * 32;
  int end = n0 + 32;
  if (end > NNODES) end = NNODES;
  int cur = gid[n0];
  float acc = 0.f;
  for (int n = n0; n < end; ++n) {
    int g = gid[n];
    if (g != cur) {
      atomicAdd(&pooled[cur * DIM + j], acc);
      acc = 0.f;
      cur = g;
    }
    acc += bf2f(h[(size_t)n * DIM + j]);
  }
  atomicAdd(&pooled[cur * DIM + j], acc);
}

// ---------------- logits + sigmoid ----------------
__global__ __launch_bounds__(128) void cls_kernel(const float* __restrict__ pooled,
                                                  const float* __restrict__ Wc,
                                                  const float* __restrict__ bc,
                                                  float* __restrict__ out) {
  int g = threadIdx.x;
  float acc = bc[0];
  for (int k = 0; k < DIM; ++k) acc = fmaf(pooled[g * DIM + k], Wc[k], acc);
  out[g] = 1.f / (1.f + __expf(-acc));
}

extern "C" void kernel_launch(void* const* d_in, const int* in_sizes, int n_in,
                              void* d_out, int out_size, void* d_ws, size_t ws_size,
                              hipStream_t stream) {
  const float* features = (const float*)d_in[0];
  const int* esrc = (const int*)d_in[1];
  const int* edst = (const int*)d_in[2];
  const int* etyp = (const int*)d_in[3];
  const int* gids = (const int*)d_in[4];
  const float* W_edge = (const float*)d_in[5];
  const float* W_ih = (const float*)d_in[6];
  const float* W_hh = (const float*)d_in[7];
  const float* b_ih = (const float*)d_in[8];
  const float* b_hh = (const float*)d_in[9];
  const float* W_cls = (const float*)d_in[10];
  const float* b_cls = (const float*)d_in[11];
  float* out = (float*)d_out;

  const size_t nd = (size_t)NNODES * DIM;
  char* p = (char*)d_ws;
  auto take = [&](size_t bytes) {
    char* q = p;
    p += (bytes + 15) & ~(size_t)15;
    return (void*)q;
  };
  unsigned short* ht4 = (unsigned short*)take(NETYPES * nd * 2);   // 102.4 MB
  unsigned short* abf = (unsigned short*)take(nd * 2);             // 25.6 MB
  unsigned short* hbf = (unsigned short*)take(nd * 2);             // 25.6 MB
  unsigned short* WeT = (unsigned short*)take(NETYPES * DIM * DIM * 2);
  unsigned short* Wihb = (unsigned short*)take(384 * DIM * 2);
  unsigned short* Whhb = (unsigned short*)take(384 * DIM * 2);
  int* rp = (int*)take((NBINS + 1) * 4);
  int* cursor = (int*)take(NBINS * 4);  // doubles as histogram bins
  int* bsum = (int*)take(512 * 4);
  int* boffs = (int*)take(512 * 4);
  int* esrc_s = (int*)take(NEDGES * 4);
  float* pooled = (float*)take(NGRAPHS * DIM * 4);
  size_t need = (size_t)(p - (char*)d_ws);

  if (ws_size < need) {
    fill_kernel<<<(out_size + 127) / 128, 128, 0, stream>>>(out, out_size, 0.5f);
    return;
  }

  // converts
  cvt_h_kernel<<<(int)(nd / 4 + 255) / 256, 256, 0, stream>>>(features, hbf, (int)(nd / 4));
  cvt_we_kernel<<<(NETYPES * DIM * DIM + 255) / 256, 256, 0, stream>>>(W_edge, WeT);
  cvt_w_kernel<<<(384 * DIM + 255) / 256, 256, 0, stream>>>(W_ih, Wihb, 384 * DIM);
  cvt_w_kernel<<<(384 * DIM + 255) / 256, 256, 0, stream>>>(W_hh, Whhb, 384 * DIM);

  // CSR build (counting sort by (etype, dst))
  hipMemsetAsync(cursor, 0, (size_t)NBINS * 4, stream);
  hist_kernel<<<(NEDGES + 255) / 256, 256, 0, stream>>>(edst, etyp, cursor);
  scan1_kernel<<<SCAN_BLK, 256, 0, stream>>>(cursor, rp, bsum);
  scan2_kernel<<<1, 512, 0, stream>>>(bsum, boffs, rp);
  scan3_kernel<<<SCAN_BLK, 256, 0, stream>>>(rp, boffs);
  hipMemcpyAsync(cursor, rp, (size_t)NBINS * 4, hipMemcpyDeviceToDevice, stream);
  fill_edges_kernel<<<(NEDGES + 255) / 256, 256, 0, stream>>>(esrc, edst, etyp, cursor, esrc_s);

  for (int s = 0; s < NSTEPS; ++s) {
    gemm_ht4_kernel<<<dim3((NNODES + 127) / 128, NETYPES), 256, 0, stream>>>(hbf, WeT, ht4);
    aggregate_kernel<<<(NNODES * 64 + 255) / 256, 256, 0, stream>>>(ht4, rp, esrc_s, abf);
    gru_mfma_kernel<<<NNODES / 32, 256, 0, stream>>>(abf, hbf, Wihb, Whhb, b_ih, b_hh);
  }

  hipMemsetAsync(pooled, 0, (size_t)NGRAPHS * DIM * 4, stream);
  pool_kernel<<<(NNODES + 31) / 32, 128, 0, stream>>>(hbf, gids, pooled);
  cls_kernel<<<1, 128, 0, stream>>>(pooled, W_cls, b_cls, out);
}

// Round 4
// 1891.145 us; speedup vs baseline: 5.7388x; 1.2758x over previous
//
#include <hip/hip_runtime.h>
#include <cstdint>

#define NNODES 100000
#define NEDGES 600000
#define NETYPES 4
#define DIM 128
#define NSTEPS 8
#define NGRAPHS 128
#define NBINS (NETYPES * NNODES)
#define SCAN_BLK 391  // ceil(NBINS/1024)
#define NTILES (NNODES / 32)

typedef short s16x8 __attribute__((ext_vector_type(8)));
typedef float f32x4 __attribute__((ext_vector_type(4)));

#define MFMA(a, b, c) __builtin_amdgcn_mfma_f32_16x16x32_bf16(a, b, c, 0, 0, 0)

static __device__ inline unsigned short f2bf(float x) {
  unsigned int u = __float_as_uint(x);
  unsigned int r = (u + 0x7FFFu + ((u >> 16) & 1u)) >> 16;
  return (unsigned short)r;
}
static __device__ inline float bf2f(unsigned short b) {
  return __uint_as_float(((unsigned int)b) << 16);
}

// ---------------- diagnostic fill ----------------
__global__ __launch_bounds__(128) void fill_kernel(float* __restrict__ out, int n, float v) {
  int i = blockIdx.x * 128 + threadIdx.x;
  if (i < n) out[i] = v;
}

// ---------------- fp32 -> bf16 converts ----------------
__global__ __launch_bounds__(256) void cvt_h_kernel(const float* __restrict__ f,
                                                    unsigned short* __restrict__ h, int n4) {
  int i = blockIdx.x * 256 + threadIdx.x;
  if (i < n4) {
    float4 v = ((const float4*)f)[i];
    ushort4 u = {f2bf(v.x), f2bf(v.y), f2bf(v.z), f2bf(v.w)};
    ((ushort4*)h)[i] = u;
  }
}

// W_edge [e][d][h] fp32 -> WeT [e][h][d] bf16 (j-major, k-contiguous)
__global__ __launch_bounds__(256) void cvt_we_kernel(const float* __restrict__ W,
                                                     unsigned short* __restrict__ WT) {
  int i = blockIdx.x * 256 + threadIdx.x;
  if (i < NETYPES * DIM * DIM) {
    int e = i >> 14;
    int r = i & 16383;
    int d = r >> 7;   // k
    int j = r & 127;  // output col
    WT[(e << 14) + (j << 7) + d] = f2bf(W[i]);
  }
}

__global__ __launch_bounds__(256) void cvt_w_kernel(const float* __restrict__ W,
                                                    unsigned short* __restrict__ Wb, int n) {
  int i = blockIdx.x * 256 + threadIdx.x;
  if (i < n) Wb[i] = f2bf(W[i]);
}

// ---------------- CSR build: histogram / scan / fill ----------------
__global__ __launch_bounds__(256) void hist_kernel(const int* __restrict__ edst,
                                                   const int* __restrict__ etyp,
                                                   int* __restrict__ bins) {
  int e = blockIdx.x * 256 + threadIdx.x;
  if (e < NEDGES) atomicAdd(&bins[etyp[e] * NNODES + edst[e]], 1);
}

__global__ __launch_bounds__(256) void scan1_kernel(const int* __restrict__ bins,
                                                    int* __restrict__ rp,
                                                    int* __restrict__ bsum) {
  __shared__ int sh[256];
  int b = blockIdx.x, t = threadIdx.x;
  int base = b * 1024 + t * 4;
  int v0 = 0, v1 = 0, v2 = 0, v3 = 0;
  if (base + 3 < NBINS) {
    int4 q = *(const int4*)(bins + base);
    v0 = q.x; v1 = q.y; v2 = q.z; v3 = q.w;
  } else {
    if (base < NBINS) v0 = bins[base];
    if (base + 1 < NBINS) v1 = bins[base + 1];
    if (base + 2 < NBINS) v2 = bins[base + 2];
  }
  int s = v0 + v1 + v2 + v3;
  sh[t] = s;
  __syncthreads();
  for (int off = 1; off < 256; off <<= 1) {
    int x = (t >= off) ? sh[t - off] : 0;
    __syncthreads();
    if (t >= off) sh[t] += x;
    __syncthreads();
  }
  int run = sh[t] - s;
  if (t == 255) bsum[b] = sh[255];
  if (base < NBINS) rp[base] = run;
  run += v0;
  if (base + 1 < NBINS) rp[base + 1] = run;
  run += v1;
  if (base + 2 < NBINS) rp[base + 2] = run;
  run += v2;
  if (base + 3 < NBINS) rp[base + 3] = run;
}

__global__ __launch_bounds__(512) void scan2_kernel(const int* __restrict__ bsum,
                                                    int* __restrict__ boffs,
                                                    int* __restrict__ rp) {
  __shared__ int sh[512];
  int t = threadIdx.x;
  int v = (t < SCAN_BLK) ? bsum[t] : 0;
  sh[t] = v;
  __syncthreads();
  for (int off = 1; off < 512; off <<= 1) {
    int x = (t >= off) ? sh[t - off] : 0;
    __syncthreads();
    if (t >= off) sh[t] += x;
    __syncthreads();
  }
  if (t < SCAN_BLK) boffs[t] = sh[t] - v;
  if (t == SCAN_BLK - 1) rp[NBINS] = sh[t];
}

__global__ __launch_bounds__(256) void scan3_kernel(int* __restrict__ rp,
                                                    const int* __restrict__ boffs) {
  int b = blockIdx.x, t = threadIdx.x;
  int base = b * 1024 + t * 4;
  int off = boffs[b];
#pragma unroll
  for (int i = 0; i < 4; ++i)
    if (base + i < NBINS) rp[base + i] += off;
}

__global__ __launch_bounds__(256) void fill_edges_kernel(const int* __restrict__ esrc,
                                                         const int* __restrict__ edst,
                                                         const int* __restrict__ etyp,
                                                         int* __restrict__ cursor,
                                                         int* __restrict__ esrc_s) {
  int e = blockIdx.x * 256 + threadIdx.x;
  if (e < NEDGES) {
    int slot = atomicAdd(&cursor[etyp[e] * NNODES + edst[e]], 1);
    esrc_s[slot] = esrc[e];
  }
}

// ---------------- ht4[ty] = h @ W_edge[ty], weight-hoisted persistent ------
// block 512 (8 waves), wave = 16 j-cols x 4 etypes; grid-stride over 32-node tiles.
__global__ __launch_bounds__(512, 3) void gemm_ht4_kernel(const unsigned short* __restrict__ hbf,
                                                          const unsigned short* __restrict__ WeT,
                                                          unsigned short* __restrict__ ht4) {
  const int wid = threadIdx.x >> 6, lane = threadIdx.x & 63;
  const int l15 = lane & 15, kg = lane >> 4;
  const int j0 = wid * 16;
  const int jb = j0 + kg * 4;

  s16x8 wf[4][4];  // [ty][c], hoisted once
#pragma unroll
  for (int ty = 0; ty < 4; ++ty)
#pragma unroll
    for (int c = 0; c < 4; ++c)
      wf[ty][c] = *(const s16x8*)(WeT + (ty << 14) + ((j0 + l15) << 7) + c * 32 + kg * 8);

  for (int tile = blockIdx.x; tile < NTILES; tile += gridDim.x) {
    const int n0 = tile * 32;
    f32x4 acc[4][2];
#pragma unroll
    for (int ty = 0; ty < 4; ++ty)
#pragma unroll
      for (int nb = 0; nb < 2; ++nb) acc[ty][nb] = (f32x4){0.f, 0.f, 0.f, 0.f};

#pragma unroll
    for (int c = 0; c < 4; ++c) {
      s16x8 hf[2];
#pragma unroll
      for (int nb = 0; nb < 2; ++nb)
        hf[nb] = *(const s16x8*)(hbf + (size_t)(n0 + nb * 16 + l15) * DIM + c * 32 + kg * 8);
#pragma unroll
      for (int ty = 0; ty < 4; ++ty) {
        acc[ty][0] = MFMA(wf[ty][c], hf[0], acc[ty][0]);
        acc[ty][1] = MFMA(wf[ty][c], hf[1], acc[ty][1]);
      }
    }
#pragma unroll
    for (int ty = 0; ty < 4; ++ty) {
#pragma unroll
      for (int nb = 0; nb < 2; ++nb) {
        int n = n0 + nb * 16 + l15;
        ushort4 u = {f2bf(acc[ty][nb][0]), f2bf(acc[ty][nb][1]),
                     f2bf(acc[ty][nb][2]), f2bf(acc[ty][nb][3])};
        *(ushort4*)(ht4 + (size_t)ty * NNODES * DIM + (size_t)n * DIM + jb) = u;
      }
    }
  }
}

// ---------------- a[d] = sum over CSR in-edges of ht4[ty][src] -------------
__global__ __launch_bounds__(256) void aggregate_kernel(const unsigned short* __restrict__ ht4,
                                                        const int* __restrict__ rp,
                                                        const int* __restrict__ esrc_s,
                                                        unsigned short* __restrict__ abf) {
  int w = (blockIdx.x * 256 + threadIdx.x) >> 6;
  int lane = threadIdx.x & 63;
  if (w >= NNODES) return;
  float ax = 0.f, ay = 0.f;
#pragma unroll
  for (int ty = 0; ty < NETYPES; ++ty) {
    int beg = rp[ty * NNODES + w];
    int end = rp[ty * NNODES + w + 1];
    const unsigned short* base = ht4 + (size_t)ty * NNODES * DIM;
    for (int e = beg; e < end; ++e) {
      int s = esrc_s[e];
      ushort2 u = *(const ushort2*)(base + (size_t)s * DIM + lane * 2);
      ax += bf2f(u.x);
      ay += bf2f(u.y);
    }
  }
  unsigned int packed = ((unsigned int)f2bf(ay) << 16) | (unsigned int)f2bf(ax);
  *(unsigned int*)(abf + (size_t)w * DIM + lane * 2) = packed;
}

// ---------------- fused GRU via MFMA, weight-hoisted persistent ------------
// block 512 (8 waves), wave = 16 j-cols of all 3 gates x both matrices.
__global__ __launch_bounds__(512, 2) void gru_mfma_kernel(const unsigned short* __restrict__ abf,
                                                          unsigned short* __restrict__ hbf,
                                                          const unsigned short* __restrict__ Wih,
                                                          const unsigned short* __restrict__ Whh,
                                                          const float* __restrict__ b_ih,
                                                          const float* __restrict__ b_hh) {
  const int wid = threadIdx.x >> 6, lane = threadIdx.x & 63;
  const int l15 = lane & 15, kg = lane >> 4;
  const int j0 = wid * 16;
  const int jb = j0 + kg * 4;

  s16x8 wI[3][4], wH[3][4];  // hoisted once: [gate][c]
#pragma unroll
  for (int g = 0; g < 3; ++g)
#pragma unroll
    for (int c = 0; c < 4; ++c) {
      int jrow = g * 128 + j0 + l15;
      wI[g][c] = *(const s16x8*)(Wih + (jrow << 7) + c * 32 + kg * 8);
      wH[g][c] = *(const s16x8*)(Whh + (jrow << 7) + c * 32 + kg * 8);
    }
  float4 bir = *(const float4*)(b_ih + jb);
  float4 biz = *(const float4*)(b_ih + 128 + jb);
  float4 bin_ = *(const float4*)(b_ih + 256 + jb);
  float4 bhr = *(const float4*)(b_hh + jb);
  float4 bhz = *(const float4*)(b_hh + 128 + jb);
  float4 bhn = *(const float4*)(b_hh + 256 + jb);

  for (int tile = blockIdx.x; tile < NTILES; tile += gridDim.x) {
    const int n0 = tile * 32;
    f32x4 gi[3][2], gh[3][2];  // [gate][nb]
#pragma unroll
    for (int g = 0; g < 3; ++g)
#pragma unroll
      for (int nb = 0; nb < 2; ++nb) {
        gi[g][nb] = (f32x4){0.f, 0.f, 0.f, 0.f};
        gh[g][nb] = (f32x4){0.f, 0.f, 0.f, 0.f};
      }

#pragma unroll
    for (int c = 0; c < 4; ++c) {
      s16x8 afr[2], hfr[2];
#pragma unroll
      for (int nb = 0; nb < 2; ++nb) {
        int r = n0 + nb * 16 + l15;
        afr[nb] = *(const s16x8*)(abf + (size_t)r * DIM + c * 32 + kg * 8);
        hfr[nb] = *(const s16x8*)(hbf + (size_t)r * DIM + c * 32 + kg * 8);
      }
#pragma unroll
      for (int g = 0; g < 3; ++g) {
        gi[g][0] = MFMA(wI[g][c], afr[0], gi[g][0]);
        gi[g][1] = MFMA(wI[g][c], afr[1], gi[g][1]);
        gh[g][0] = MFMA(wH[g][c], hfr[0], gh[g][0]);
        gh[g][1] = MFMA(wH[g][c], hfr[1], gh[g][1]);
      }
    }

    __syncthreads();  // all h reads of this tile done before any h writes

#pragma unroll
    for (int nb = 0; nb < 2; ++nb) {
      int n = n0 + nb * 16 + l15;
      ushort4 hold4 = *(const ushort4*)(hbf + (size_t)n * DIM + jb);
      ushort4 outu;
#pragma unroll
      for (int reg = 0; reg < 4; ++reg) {
        float ir = gi[0][nb][reg] + ((const float*)&bir)[reg];
        float iz = gi[1][nb][reg] + ((const float*)&biz)[reg];
        float in_ = gi[2][nb][reg] + ((const float*)&bin_)[reg];
        float hr = gh[0][nb][reg] + ((const float*)&bhr)[reg];
        float hz = gh[1][nb][reg] + ((const float*)&bhz)[reg];
        float hn = gh[2][nb][reg] + ((const float*)&bhn)[reg];
        float r = 1.f / (1.f + __expf(-(ir + hr)));
        float z = 1.f / (1.f + __expf(-(iz + hz)));
        float x = in_ + r * hn;
        float ex = __expf(2.f * x);
        float nn = 1.f - 2.f / (ex + 1.f);  // tanh
        float ho = bf2f(((const unsigned short*)&hold4)[reg]);
        float hv = (1.f - z) * nn + z * ho;
        ((unsigned short*)&outu)[reg] = f2bf(hv);
      }
      *(ushort4*)(hbf + (size_t)n * DIM + jb) = outu;
    }
  }
}

// ---------------- pooled[g] = sum_{gid[n]==g} h[n] ----------------
__global__ __launch_bounds__(128) void pool_kernel(const unsigned short* __restrict__ h,
                                                   const int* __restrict__ gid,
                                                   float* __restrict__ pooled) {
  int j = threadIdx.x;
  int n0 = blockIdx.x * 32;
  int end = n0 + 32;
  if (end > NNODES) end = NNODES;
  int cur = gid[n0];
  float acc = 0.f;
  for (int n = n0; n < end; ++n) {
    int g = gid[n];
    if (g != cur) {
      atomicAdd(&pooled[cur * DIM + j], acc);
      acc = 0.f;
      cur = g;
    }
    acc += bf2f(h[(size_t)n * DIM + j]);
  }
  atomicAdd(&pooled[cur * DIM + j], acc);
}

// ---------------- logits + sigmoid ----------------
__global__ __launch_bounds__(128) void cls_kernel(const float* __restrict__ pooled,
                                                  const float* __restrict__ Wc,
                                                  const float* __restrict__ bc,
                                                  float* __restrict__ out) {
  int g = threadIdx.x;
  float acc = bc[0];
  for (int k = 0; k < DIM; ++k) acc = fmaf(pooled[g * DIM + k], Wc[k], acc);
  out[g] = 1.f / (1.f + __expf(-acc));
}

extern "C" void kernel_launch(void* const* d_in, const int* in_sizes, int n_in,
                              void* d_out, int out_size, void* d_ws, size_t ws_size,
                              hipStream_t stream) {
  const float* features = (const float*)d_in[0];
  const int* esrc = (const int*)d_in[1];
  const int* edst = (const int*)d_in[2];
  const int* etyp = (const int*)d_in[3];
  const int* gids = (const int*)d_in[4];
  const float* W_edge = (const float*)d_in[5];
  const float* W_ih = (const float*)d_in[6];
  const float* W_hh = (const float*)d_in[7];
  const float* b_ih = (const float*)d_in[8];
  const float* b_hh = (const float*)d_in[9];
  const float* W_cls = (const float*)d_in[10];
  const float* b_cls = (const float*)d_in[11];
  float* out = (float*)d_out;

  const size_t nd = (size_t)NNODES * DIM;
  char* p = (char*)d_ws;
  auto take = [&](size_t bytes) {
    char* q = p;
    p += (bytes + 15) & ~(size_t)15;
    return (void*)q;
  };
  unsigned short* ht4 = (unsigned short*)take(NETYPES * nd * 2);  // 102.4 MB
  unsigned short* abf = (unsigned short*)take(nd * 2);            // 25.6 MB
  unsigned short* hbf = (unsigned short*)take(nd * 2);            // 25.6 MB
  unsigned short* WeT = (unsigned short*)take(NETYPES * DIM * DIM * 2);
  unsigned short* Wihb = (unsigned short*)take(384 * DIM * 2);
  unsigned short* Whhb = (unsigned short*)take(384 * DIM * 2);
  int* rp = (int*)take((NBINS + 1) * 4);
  int* cursor = (int*)take(NBINS * 4);
  int* bsum = (int*)take(512 * 4);
  int* boffs = (int*)take(512 * 4);
  int* esrc_s = (int*)take(NEDGES * 4);
  float* pooled = (float*)take(NGRAPHS * DIM * 4);
  size_t need = (size_t)(p - (char*)d_ws);

  if (ws_size < need) {
    fill_kernel<<<(out_size + 127) / 128, 128, 0, stream>>>(out, out_size, 0.5f);
    return;
  }

  cvt_h_kernel<<<(int)(nd / 4 + 255) / 256, 256, 0, stream>>>(features, hbf, (int)(nd / 4));
  cvt_we_kernel<<<(NETYPES * DIM * DIM + 255) / 256, 256, 0, stream>>>(W_edge, WeT);
  cvt_w_kernel<<<(384 * DIM + 255) / 256, 256, 0, stream>>>(W_ih, Wihb, 384 * DIM);
  cvt_w_kernel<<<(384 * DIM + 255) / 256, 256, 0, stream>>>(W_hh, Whhb, 384 * DIM);

  hipMemsetAsync(cursor, 0, (size_t)NBINS * 4, stream);
  hist_kernel<<<(NEDGES + 255) / 256, 256, 0, stream>>>(edst, etyp, cursor);
  scan1_kernel<<<SCAN_BLK, 256, 0, stream>>>(cursor, rp, bsum);
  scan2_kernel<<<1, 512, 0, stream>>>(bsum, boffs, rp);
  scan3_kernel<<<SCAN_BLK, 256, 0, stream>>>(rp, boffs);
  hipMemcpyAsync(cursor, rp, (size_t)NBINS * 4, hipMemcpyDeviceToDevice, stream);
  fill_edges_kernel<<<(NEDGES + 255) / 256, 256, 0, stream>>>(esrc, edst, etyp, cursor, esrc_s);

  for (int s = 0; s < NSTEPS; ++s) {
    gemm_ht4_kernel<<<1024, 512, 0, stream>>>(hbf, WeT, ht4);
    aggregate_kernel<<<(NNODES * 64 + 255) / 256, 256, 0, stream>>>(ht4, rp, esrc_s, abf);
    gru_mfma_kernel<<<1024, 512, 0, stream>>>(abf, hbf, Wihb, Whhb, b_ih, b_hh);
  }

  hipMemsetAsync(pooled, 0, (size_t)NGRAPHS * DIM * 4, stream);
  pool_kernel<<<(NNODES + 31) / 32, 128, 0, stream>>>(hbf, gids, pooled);
  cls_kernel<<<1, 128, 0, stream>>>(pooled, W_cls, b_cls, out);
}

// Round 5
// 1355.340 us; speedup vs baseline: 8.0076x; 1.3953x over previous
//
#include <hip/hip_runtime.h>
#include <cstdint>

#define NNODES 100000
#define NEDGES 600000
#define NETYPES 4
#define DIM 128
#define NSTEPS 8
#define NGRAPHS 128
#define NBINS (NETYPES * NNODES)
#define SCAN_BLK 391  // ceil(NBINS/1024)
#define NTILES (NNODES / 32)
#define PGRID 512

typedef short s16x8 __attribute__((ext_vector_type(8)));
typedef float f32x4 __attribute__((ext_vector_type(4)));

#define MFMA(a, b, c) __builtin_amdgcn_mfma_f32_16x16x32_bf16(a, b, c, 0, 0, 0)

static __device__ inline unsigned short f2bf(float x) {
  unsigned int u = __float_as_uint(x);
  unsigned int r = (u + 0x7FFFu + ((u >> 16) & 1u)) >> 16;
  return (unsigned short)r;
}
static __device__ inline float bf2f(unsigned short b) {
  return __uint_as_float(((unsigned int)b) << 16);
}

// ---------------- diagnostic fill ----------------
__global__ __launch_bounds__(128) void fill_kernel(float* __restrict__ out, int n, float v) {
  int i = blockIdx.x * 128 + threadIdx.x;
  if (i < n) out[i] = v;
}

// ---------------- fp32 -> bf16 converts ----------------
__global__ __launch_bounds__(256) void cvt_h_kernel(const float* __restrict__ f,
                                                    unsigned short* __restrict__ h, int n4) {
  int i = blockIdx.x * 256 + threadIdx.x;
  if (i < n4) {
    float4 v = ((const float4*)f)[i];
    ushort4 u = {f2bf(v.x), f2bf(v.y), f2bf(v.z), f2bf(v.w)};
    ((ushort4*)h)[i] = u;
  }
}

// W_edge [e][d][h] fp32 -> WeT [e][h][d] bf16 (j-major, k-contiguous)
__global__ __launch_bounds__(256) void cvt_we_kernel(const float* __restrict__ W,
                                                     unsigned short* __restrict__ WT) {
  int i = blockIdx.x * 256 + threadIdx.x;
  if (i < NETYPES * DIM * DIM) {
    int e = i >> 14;
    int r = i & 16383;
    int d = r >> 7;   // k
    int j = r & 127;  // output col
    WT[(e << 14) + (j << 7) + d] = f2bf(W[i]);
  }
}

__global__ __launch_bounds__(256) void cvt_w_kernel(const float* __restrict__ W,
                                                    unsigned short* __restrict__ Wb, int n) {
  int i = blockIdx.x * 256 + threadIdx.x;
  if (i < n) Wb[i] = f2bf(W[i]);
}

// ---------------- CSR build: histogram / scan / fill ----------------
__global__ __launch_bounds__(256) void hist_kernel(const int* __restrict__ edst,
                                                   const int* __restrict__ etyp,
                                                   int* __restrict__ bins) {
  int e = blockIdx.x * 256 + threadIdx.x;
  if (e < NEDGES) atomicAdd(&bins[etyp[e] * NNODES + edst[e]], 1);
}

__global__ __launch_bounds__(256) void scan1_kernel(const int* __restrict__ bins,
                                                    int* __restrict__ rp,
                                                    int* __restrict__ bsum) {
  __shared__ int sh[256];
  int b = blockIdx.x, t = threadIdx.x;
  int base = b * 1024 + t * 4;
  int v0 = 0, v1 = 0, v2 = 0, v3 = 0;
  if (base + 3 < NBINS) {
    int4 q = *(const int4*)(bins + base);
    v0 = q.x; v1 = q.y; v2 = q.z; v3 = q.w;
  } else {
    if (base < NBINS) v0 = bins[base];
    if (base + 1 < NBINS) v1 = bins[base + 1];
    if (base + 2 < NBINS) v2 = bins[base + 2];
  }
  int s = v0 + v1 + v2 + v3;
  sh[t] = s;
  __syncthreads();
  for (int off = 1; off < 256; off <<= 1) {
    int x = (t >= off) ? sh[t - off] : 0;
    __syncthreads();
    if (t >= off) sh[t] += x;
    __syncthreads();
  }
  int run = sh[t] - s;
  if (t == 255) bsum[b] = sh[255];
  if (base < NBINS) rp[base] = run;
  run += v0;
  if (base + 1 < NBINS) rp[base + 1] = run;
  run += v1;
  if (base + 2 < NBINS) rp[base + 2] = run;
  run += v2;
  if (base + 3 < NBINS) rp[base + 3] = run;
}

__global__ __launch_bounds__(512) void scan2_kernel(const int* __restrict__ bsum,
                                                    int* __restrict__ boffs,
                                                    int* __restrict__ rp) {
  __shared__ int sh[512];
  int t = threadIdx.x;
  int v = (t < SCAN_BLK) ? bsum[t] : 0;
  sh[t] = v;
  __syncthreads();
  for (int off = 1; off < 512; off <<= 1) {
    int x = (t >= off) ? sh[t - off] : 0;
    __syncthreads();
    if (t >= off) sh[t] += x;
    __syncthreads();
  }
  if (t < SCAN_BLK) boffs[t] = sh[t] - v;
  if (t == SCAN_BLK - 1) rp[NBINS] = sh[t];
}

__global__ __launch_bounds__(256) void scan3_kernel(int* __restrict__ rp,
                                                    const int* __restrict__ boffs) {
  int b = blockIdx.x, t = threadIdx.x;
  int base = b * 1024 + t * 4;
  int off = boffs[b];
#pragma unroll
  for (int i = 0; i < 4; ++i)
    if (base + i < NBINS) rp[base + i] += off;
}

__global__ __launch_bounds__(256) void fill_edges_kernel(const int* __restrict__ esrc,
                                                         const int* __restrict__ edst,
                                                         const int* __restrict__ etyp,
                                                         int* __restrict__ cursor,
                                                         int* __restrict__ esrc_s) {
  int e = blockIdx.x * 256 + threadIdx.x;
  if (e < NEDGES) {
    int slot = atomicAdd(&cursor[etyp[e] * NNODES + edst[e]], 1);
    esrc_s[slot] = esrc[e];
  }
}

// ---------------- K1: agg4[ty][d] = sum_{e:(s,d,ty)} h[s]  (gather from hot h)
__global__ __launch_bounds__(256) void agg4_kernel(const unsigned short* __restrict__ hbf,
                                                   const int* __restrict__ rp,
                                                   const int* __restrict__ esrc_s,
                                                   unsigned short* __restrict__ agg4) {
  int w = (blockIdx.x * 256 + threadIdx.x) >> 6;
  int lane = threadIdx.x & 63;
  if (w >= NNODES) return;
#pragma unroll
  for (int ty = 0; ty < NETYPES; ++ty) {
    int beg = rp[ty * NNODES + w];
    int end = rp[ty * NNODES + w + 1];
    float ax = 0.f, ay = 0.f;
    for (int e = beg; e < end; ++e) {
      int s = esrc_s[e];
      ushort2 u = *(const ushort2*)(hbf + (size_t)s * DIM + lane * 2);
      ax += bf2f(u.x);
      ay += bf2f(u.y);
    }
    unsigned int packed = ((unsigned int)f2bf(ay) << 16) | (unsigned int)f2bf(ax);
    *(unsigned int*)(agg4 + (size_t)ty * NNODES * DIM + (size_t)w * DIM + lane * 2) = packed;
  }
}

// ---------------- K2: abf = sum_ty agg4[ty] @ W_ty  (LDS-staged, pipelined)
// block 512 (8 waves, wave = 16 j-cols), persistent grid-stride over 32-node tiles.
__global__ __launch_bounds__(512, 2) void transform_kernel(const unsigned short* __restrict__ agg4,
                                                           const unsigned short* __restrict__ WeT,
                                                           unsigned short* __restrict__ abf) {
  __shared__ s16x8 lds[2][2048];  // 2 x 32KB: [ty][row][128] bf16, 16B-swizzled
  const int t = threadIdx.x;
  const int wid = t >> 6, lane = t & 63;
  const int l15 = lane & 15, kg = lane >> 4;
  const int j0 = wid * 16, jb = j0 + kg * 4;

  s16x8 wf[4][4];
#pragma unroll
  for (int ty = 0; ty < 4; ++ty)
#pragma unroll
    for (int c = 0; c < 4; ++c)
      wf[ty][c] = *(const s16x8*)(WeT + (ty << 14) + ((j0 + l15) << 7) + c * 32 + kg * 8);

  // staging: 2048 16B-chunks; 4 per thread
  int chk[4], lby[4];
#pragma unroll
  for (int i = 0; i < 4; ++i) {
    chk[i] = t + i * 512;
    int row = (chk[i] & 511) >> 4;    // row within ty-plane (0..31)
    int w16 = chk[i] & 15;
    lby[i] = (chk[i] >> 9) * 8192 + row * 256 + ((w16 ^ (row & 7)) << 4);
  }
  auto gsrc = [&](int i, int tile) -> const s16x8* {
    int ty = chk[i] >> 9;
    int row = (chk[i] & 511) >> 4;
    int w16 = chk[i] & 15;
    return (const s16x8*)(agg4 + (size_t)ty * NNODES * DIM +
                          (size_t)(tile * 32 + row) * DIM + w16 * 8);
  };

  int tile = blockIdx.x;
  if (tile >= NTILES) return;
  s16x8 st[4];
#pragma unroll
  for (int i = 0; i < 4; ++i) st[i] = *gsrc(i, tile);
#pragma unroll
  for (int i = 0; i < 4; ++i) *(s16x8*)((char*)&lds[0][0] + lby[i]) = st[i];
  int nx = tile + gridDim.x;
  bool hasnx = nx < NTILES;
  if (hasnx)
#pragma unroll
    for (int i = 0; i < 4; ++i) st[i] = *gsrc(i, nx);
  __syncthreads();
  int cur = 0;

  while (true) {
    if (hasnx) {
#pragma unroll
      for (int i = 0; i < 4; ++i) *(s16x8*)((char*)&lds[cur ^ 1][0] + lby[i]) = st[i];
    }
    int nx2 = nx + gridDim.x;
    bool has2 = hasnx && (nx2 < NTILES);
    if (has2) {
#pragma unroll
      for (int i = 0; i < 4; ++i) st[i] = *gsrc(i, nx2);
    }

    f32x4 acc[2] = {(f32x4){0.f, 0.f, 0.f, 0.f}, (f32x4){0.f, 0.f, 0.f, 0.f}};
    char* B0 = (char*)&lds[cur][0];
#pragma unroll
    for (int ty = 0; ty < 4; ++ty) {
#pragma unroll
      for (int c = 0; c < 4; ++c) {
        s16x8 afr[2];
#pragma unroll
        for (int nb = 0; nb < 2; ++nb) {
          int row = nb * 16 + l15;
          afr[nb] = *(const s16x8*)(B0 + ty * 8192 + row * 256 +
                                    ((c * 64 + kg * 16) ^ ((row & 7) << 4)));
        }
        acc[0] = MFMA(wf[ty][c], afr[0], acc[0]);
        acc[1] = MFMA(wf[ty][c], afr[1], acc[1]);
      }
    }
    const int n0 = tile * 32;
#pragma unroll
    for (int nb = 0; nb < 2; ++nb) {
      int n = n0 + nb * 16 + l15;
      ushort4 u = {f2bf(acc[nb][0]), f2bf(acc[nb][1]), f2bf(acc[nb][2]), f2bf(acc[nb][3])};
      *(ushort4*)(abf + (size_t)n * DIM + jb) = u;
    }
    __syncthreads();
    if (!hasnx) break;
    tile = nx;
    nx = nx2;
    hasnx = has2;
    cur ^= 1;
  }
}

// ---------------- K3: fused GRU via MFMA (LDS-staged, pipelined) -----------
__global__ __launch_bounds__(512, 2) void gru_mfma_kernel(const unsigned short* __restrict__ abf,
                                                          unsigned short* __restrict__ hbf,
                                                          const unsigned short* __restrict__ Wih,
                                                          const unsigned short* __restrict__ Whh,
                                                          const float* __restrict__ b_ih,
                                                          const float* __restrict__ b_hh) {
  __shared__ s16x8 lds[2][1024];  // 2 x 16KB: a-plane [0,8K), h-plane [8K,16K)
  const int t = threadIdx.x;
  const int wid = t >> 6, lane = t & 63;
  const int l15 = lane & 15, kg = lane >> 4;
  const int j0 = wid * 16, jb = j0 + kg * 4;

  s16x8 wI[3][4], wH[3][4];
#pragma unroll
  for (int g = 0; g < 3; ++g)
#pragma unroll
    for (int c = 0; c < 4; ++c) {
      int jrow = g * 128 + j0 + l15;
      wI[g][c] = *(const s16x8*)(Wih + (jrow << 7) + c * 32 + kg * 8);
      wH[g][c] = *(const s16x8*)(Whh + (jrow << 7) + c * 32 + kg * 8);
    }
  float4 bir = *(const float4*)(b_ih + jb);
  float4 biz = *(const float4*)(b_ih + 128 + jb);
  float4 bin_ = *(const float4*)(b_ih + 256 + jb);
  float4 bhr = *(const float4*)(b_hh + jb);
  float4 bhz = *(const float4*)(b_hh + 128 + jb);
  float4 bhn = *(const float4*)(b_hh + 256 + jb);

  // staging: 1024 16B-chunks; 2 per thread
  int chk0 = t, chk1 = t + 512;
  int row0 = (chk0 & 511) >> 4, w160 = chk0 & 15;
  int row1 = (chk1 & 511) >> 4, w161 = chk1 & 15;
  int lb0 = (chk0 >> 9) * 8192 + row0 * 256 + ((w160 ^ (row0 & 7)) << 4);
  int lb1 = (chk1 >> 9) * 8192 + row1 * 256 + ((w161 ^ (row1 & 7)) << 4);
  // hold-read byte offset (within h-plane), swizzled, 8B granule-safe
  int hbyte_lo = (jb * 2) & 15;
  int hbyte_slot = (jb * 2) >> 4;

  int tile = blockIdx.x;
  if (tile >= NTILES) return;
  s16x8 st0, st1;
  st0 = *(const s16x8*)(((chk0 >> 9) ? hbf : abf) + (size_t)(tile * 32 + row0) * DIM + w160 * 8);
  st1 = *(const s16x8*)(((chk1 >> 9) ? hbf : abf) + (size_t)(tile * 32 + row1) * DIM + w161 * 8);
  *(s16x8*)((char*)&lds[0][0] + lb0) = st0;
  *(s16x8*)((char*)&lds[0][0] + lb1) = st1;
  int nx = tile + gridDim.x;
  bool hasnx = nx < NTILES;
  if (hasnx) {
    st0 = *(const s16x8*)(((chk0 >> 9) ? hbf : abf) + (size_t)(nx * 32 + row0) * DIM + w160 * 8);
    st1 = *(const s16x8*)(((chk1 >> 9) ? hbf : abf) + (size_t)(nx * 32 + row1) * DIM + w161 * 8);
  }
  __syncthreads();
  int cur = 0;

  while (true) {
    if (hasnx) {
      *(s16x8*)((char*)&lds[cur ^ 1][0] + lb0) = st0;
      *(s16x8*)((char*)&lds[cur ^ 1][0] + lb1) = st1;
    }
    int nx2 = nx + gridDim.x;
    bool has2 = hasnx && (nx2 < NTILES);
    if (has2) {
      st0 = *(const s16x8*)(((chk0 >> 9) ? hbf : abf) + (size_t)(nx2 * 32 + row0) * DIM + w160 * 8);
      st1 = *(const s16x8*)(((chk1 >> 9) ? hbf : abf) + (size_t)(nx2 * 32 + row1) * DIM + w161 * 8);
    }

    f32x4 gi[3][2], gh[3][2];
#pragma unroll
    for (int g = 0; g < 3; ++g)
#pragma unroll
      for (int nb = 0; nb < 2; ++nb) {
        gi[g][nb] = (f32x4){0.f, 0.f, 0.f, 0.f};
        gh[g][nb] = (f32x4){0.f, 0.f, 0.f, 0.f};
      }
    char* aB = (char*)&lds[cur][0];
    char* hB = aB + 8192;
#pragma unroll
    for (int c = 0; c < 4; ++c) {
      s16x8 afr[2], hfr[2];
#pragma unroll
      for (int nb = 0; nb < 2; ++nb) {
        int row = nb * 16 + l15;
        int off = row * 256 + ((c * 64 + kg * 16) ^ ((row & 7) << 4));
        afr[nb] = *(const s16x8*)(aB + off);
        hfr[nb] = *(const s16x8*)(hB + off);
      }
#pragma unroll
      for (int g = 0; g < 3; ++g) {
        gi[g][0] = MFMA(wI[g][c], afr[0], gi[g][0]);
        gi[g][1] = MFMA(wI[g][c], afr[1], gi[g][1]);
        gh[g][0] = MFMA(wH[g][c], hfr[0], gh[g][0]);
        gh[g][1] = MFMA(wH[g][c], hfr[1], gh[g][1]);
      }
    }

    const int n0 = tile * 32;
#pragma unroll
    for (int nb = 0; nb < 2; ++nb) {
      int row = nb * 16 + l15;
      int n = n0 + row;
      int hb = row * 256 + ((hbyte_slot << 4) ^ ((row & 7) << 4)) + hbyte_lo;
      ushort4 hold4 = *(const ushort4*)(hB + hb);
      ushort4 outu;
#pragma unroll
      for (int reg = 0; reg < 4; ++reg) {
        float ir = gi[0][nb][reg] + ((const float*)&bir)[reg];
        float iz = gi[1][nb][reg] + ((const float*)&biz)[reg];
        float in_ = gi[2][nb][reg] + ((const float*)&bin_)[reg];
        float hr = gh[0][nb][reg] + ((const float*)&bhr)[reg];
        float hz = gh[1][nb][reg] + ((const float*)&bhz)[reg];
        float hn = gh[2][nb][reg] + ((const float*)&bhn)[reg];
        float r = 1.f / (1.f + __expf(-(ir + hr)));
        float z = 1.f / (1.f + __expf(-(iz + hz)));
        float x = in_ + r * hn;
        float ex = __expf(2.f * x);
        float nn = 1.f - 2.f / (ex + 1.f);  // tanh
        float ho = bf2f(((const unsigned short*)&hold4)[reg]);
        float hv = (1.f - z) * nn + z * ho;
        ((unsigned short*)&outu)[reg] = f2bf(hv);
      }
      *(ushort4*)(hbf + (size_t)n * DIM + jb) = outu;
    }
    __syncthreads();
    if (!hasnx) break;
    tile = nx;
    nx = nx2;
    hasnx = has2;
    cur ^= 1;
  }
}

// ---------------- pooled[g] = sum_{gid[n]==g} h[n] ----------------
__global__ __launch_bounds__(128) void pool_kernel(const unsigned short* __restrict__ h,
                                                   const int* __restrict__ gid,
                                                   float* __restrict__ pooled) {
  int j = threadIdx.x;
  int n0 = blockIdx.x * 32;
  int end = n0 + 32;
  if (end > NNODES) end = NNODES;
  int cur = gid[n0];
  float acc = 0.f;
  for (int n = n0; n < end; ++n) {
    int g = gid[n];
    if (g != cur) {
      atomicAdd(&pooled[cur * DIM + j], acc);
      acc = 0.f;
      cur = g;
    }
    acc += bf2f(h[(size_t)n * DIM + j]);
  }
  atomicAdd(&pooled[cur * DIM + j], acc);
}

// ---------------- logits + sigmoid ----------------
__global__ __launch_bounds__(128) void cls_kernel(const float* __restrict__ pooled,
                                                  const float* __restrict__ Wc,
                                                  const float* __restrict__ bc,
                                                  float* __restrict__ out) {
  int g = threadIdx.x;
  float acc = bc[0];
  for (int k = 0; k < DIM; ++k) acc = fmaf(pooled[g * DIM + k], Wc[k], acc);
  out[g] = 1.f / (1.f + __expf(-acc));
}

extern "C" void kernel_launch(void* const* d_in, const int* in_sizes, int n_in,
                              void* d_out, int out_size, void* d_ws, size_t ws_size,
                              hipStream_t stream) {
  const float* features = (const float*)d_in[0];
  const int* esrc = (const int*)d_in[1];
  const int* edst = (const int*)d_in[2];
  const int* etyp = (const int*)d_in[3];
  const int* gids = (const int*)d_in[4];
  const float* W_edge = (const float*)d_in[5];
  const float* W_ih = (const float*)d_in[6];
  const float* W_hh = (const float*)d_in[7];
  const float* b_ih = (const float*)d_in[8];
  const float* b_hh = (const float*)d_in[9];
  const float* W_cls = (const float*)d_in[10];
  const float* b_cls = (const float*)d_in[11];
  float* out = (float*)d_out;

  const size_t nd = (size_t)NNODES * DIM;
  char* p = (char*)d_ws;
  auto take = [&](size_t bytes) {
    char* q = p;
    p += (bytes + 15) & ~(size_t)15;
    return (void*)q;
  };
  unsigned short* agg4 = (unsigned short*)take(NETYPES * nd * 2);  // 102.4 MB
  unsigned short* abf = (unsigned short*)take(nd * 2);             // 25.6 MB
  unsigned short* hbf = (unsigned short*)take(nd * 2);             // 25.6 MB
  unsigned short* WeT = (unsigned short*)take(NETYPES * DIM * DIM * 2);
  unsigned short* Wihb = (unsigned short*)take(384 * DIM * 2);
  unsigned short* Whhb = (unsigned short*)take(384 * DIM * 2);
  int* rp = (int*)take((NBINS + 1) * 4);
  int* cursor = (int*)take(NBINS * 4);
  int* bsum = (int*)take(512 * 4);
  int* boffs = (int*)take(512 * 4);
  int* esrc_s = (int*)take(NEDGES * 4);
  float* pooled = (float*)take(NGRAPHS * DIM * 4);
  size_t need = (size_t)(p - (char*)d_ws);

  if (ws_size < need) {
    fill_kernel<<<(out_size + 127) / 128, 128, 0, stream>>>(out, out_size, 0.5f);
    return;
  }

  cvt_h_kernel<<<(int)(nd / 4 + 255) / 256, 256, 0, stream>>>(features, hbf, (int)(nd / 4));
  cvt_we_kernel<<<(NETYPES * DIM * DIM + 255) / 256, 256, 0, stream>>>(W_edge, WeT);
  cvt_w_kernel<<<(384 * DIM + 255) / 256, 256, 0, stream>>>(W_ih, Wihb, 384 * DIM);
  cvt_w_kernel<<<(384 * DIM + 255) / 256, 256, 0, stream>>>(W_hh, Whhb, 384 * DIM);

  hipMemsetAsync(cursor, 0, (size_t)NBINS * 4, stream);
  hist_kernel<<<(NEDGES + 255) / 256, 256, 0, stream>>>(edst, etyp, cursor);
  scan1_kernel<<<SCAN_BLK, 256, 0, stream>>>(cursor, rp, bsum);
  scan2_kernel<<<1, 512, 0, stream>>>(bsum, boffs, rp);
  scan3_kernel<<<SCAN_BLK, 256, 0, stream>>>(rp, boffs);
  hipMemcpyAsync(cursor, rp, (size_t)NBINS * 4, hipMemcpyDeviceToDevice, stream);
  fill_edges_kernel<<<(NEDGES + 255) / 256, 256, 0, stream>>>(esrc, edst, etyp, cursor, esrc_s);

  for (int s = 0; s < NSTEPS; ++s) {
    agg4_kernel<<<(NNODES * 64 + 255) / 256, 256, 0, stream>>>(hbf, rp, esrc_s, agg4);
    transform_kernel<<<PGRID, 512, 0, stream>>>(agg4, WeT, abf);
    gru_mfma_kernel<<<PGRID, 512, 0, stream>>>(abf, hbf, Wihb, Whhb, b_ih, b_hh);
  }

  hipMemsetAsync(pooled, 0, (size_t)NGRAPHS * DIM * 4, stream);
  pool_kernel<<<(NNODES + 31) / 32, 128, 0, stream>>>(hbf, gids, pooled);
  cls_kernel<<<1, 128, 0, stream>>>(pooled, W_cls, b_cls, out);
}